// Round 9
// baseline (462.105 us; speedup 1.0000x reference)
//
#include <hip/hip_runtime.h>
#include <hip/hip_bf16.h>

#define B_ 128
#define T_ 512
#define L_ 256

// v_dot2_f32_bf16: D = S0.bf16[0]*S1.bf16[0] + S0.bf16[1]*S1.bf16[1] + S2
__device__ __forceinline__ float dot2bf16(unsigned a, unsigned b, float c) {
    float d;
    asm("v_dot2_f32_bf16 %0, %1, %2, %3" : "=v"(d) : "v"(a), "v"(b), "v"(c));
    return d;
}

__device__ __forceinline__ unsigned short f2bf(float x) {  // RNE f32->bf16
    unsigned u = __builtin_bit_cast(unsigned, x);
    return (unsigned short)((u + 0x7fff + ((u >> 16) & 1)) >> 16);
}

// Explicit physical-AGPR staging: regalloc cannot spill/sink/remat these.
#define AW(n, v) asm volatile("v_accvgpr_write_b32 a" #n ", %0" :: "v"(v) : "a" #n)
#define AR(n) __extension__({ unsigned _t;                                 \
    asm volatile("v_accvgpr_read_b32 %0, a" #n : "=v"(_t)); _t; })
#define STG4(Q, N0, N1, N2, N3) \
    AW(N0, (Q).x); AW(N1, (Q).y); AW(N2, (Q).z); AW(N3, (Q).w);
#define DOT4(Pv, acc, accb, N0, N1, N2, N3)      \
    acc  = dot2bf16((Pv).x, AR(N0), acc);        \
    accb = dot2bf16((Pv).y, AR(N1), accb);       \
    acc  = dot2bf16((Pv).z, AR(N2), acc);        \
    accb = dot2bf16((Pv).w, AR(N3), accb);

// ---------------------------------------------------------------------------
// Kernel A: ETg[m][l] = bf16(exp(trans[l][m]))  (transposed)
// ---------------------------------------------------------------------------
__global__ __launch_bounds__(256) void k_exptrans(const float* __restrict__ trans,
                                                  unsigned short* __restrict__ ETg) {
    int m = blockIdx.x, l = threadIdx.x;
    ETg[m * L_ + l] = f2bf(__expf(trans[l * L_ + m]));
}

// ---------------------------------------------------------------------------
// Kernel B: labels from one-hot y_true (one wave per row)
// ---------------------------------------------------------------------------
__global__ __launch_bounds__(256) void k_labels(const float* __restrict__ y_true,
                                                int* __restrict__ labels) {
    int wid = threadIdx.x >> 6, lane = threadIdx.x & 63;
    int r = blockIdx.x * 4 + wid;
    const float4* row = (const float4*)(y_true + (size_t)r * L_);
    float4 v = row[lane];
    int loc = -1;
    if (v.x > 0.5f) loc = lane * 4 + 0;
    if (v.y > 0.5f) loc = lane * 4 + 1;
    if (v.z > 0.5f) loc = lane * 4 + 2;
    if (v.w > 0.5f) loc = lane * 4 + 3;
    unsigned long long m = __ballot(loc >= 0);
    int src = __ffsll(m) - 1;
    int lab = __shfl(loc, src, 64);
    if (lane == 0) labels[r] = lab;
}

// ---------------------------------------------------------------------------
// Kernel C: path_score
// ---------------------------------------------------------------------------
__global__ __launch_bounds__(256) void k_path(const float* __restrict__ y_pre,
                                              const float* __restrict__ trans,
                                              const int* __restrict__ labels,
                                              float* __restrict__ path) {
    int b = blockIdx.x, tid = threadIdx.x;
    const int* lb = labels + b * T_;
    float acc = 0.f;
    for (int t = tid; t < T_; t += 256) {
        int l1 = lb[t];
        acc += y_pre[((size_t)b * T_ + t) * L_ + l1];
        if (t + 1 < T_) acc += trans[l1 * L_ + lb[t + 1]];
    }
#pragma unroll
    for (int off = 1; off < 64; off <<= 1) acc += __shfl_xor(acc, off, 64);
    __shared__ float red[4];
    int wid = tid >> 6, lane = tid & 63;
    if (lane == 0) red[wid] = acc;
    __syncthreads();
    if (tid == 0) path[b] = red[0] + red[1] + red[2] + red[3];
}

// ---------------------------------------------------------------------------
// Kernel D: forward recursion, 8-wave 8-way l-split, ET in PHYSICAL AGPRs.
// Rounds 2-8: every SSA-level attempt to keep ET register-resident was
// defeated (load-sinking / spill / scratch demotion; VGPR_Count 52-140 while
// ET needs 64+). Fix: stage ET into hard-coded a0..a63 via v_accvgpr_write;
// physical registers named in asm are invisible to regalloc — they CANNOT
// be spilled or rematerialized. Loop reads them back with v_accvgpr_read
// (1 VALU op) + dot2. gfx950 unified RF: 64 AGPR + ~55 VGPR fits 8 waves.
// ---------------------------------------------------------------------------
__global__ void __launch_bounds__(512, 2)
k_forward(const float* __restrict__ yp_all,
          const unsigned short* __restrict__ ETg,
          const float* __restrict__ path,
          float* __restrict__ out) {
    int b = blockIdx.x, tid = threadIdx.x;
    int c = tid >> 6;          // wave id = l-chunk [32c, 32c+32)
    int i = tid & 63;          // lane; owned rows {i, i+64, i+128, i+192}
    const float* yp = yp_all + (size_t)b * T_ * L_;

    // Stage ET chunk (4 rows x 32 l = 64 dwords of bf16x2) into a0..a63.
    {
        const uint4* s0 = (const uint4*)(ETg + (size_t)(i      ) * L_ + 32 * c);
        const uint4* s1 = (const uint4*)(ETg + (size_t)(i +  64) * L_ + 32 * c);
        const uint4* s2 = (const uint4*)(ETg + (size_t)(i + 128) * L_ + 32 * c);
        const uint4* s3 = (const uint4*)(ETg + (size_t)(i + 192) * L_ + 32 * c);
        uint4 q;
        q = s0[0]; STG4(q,  0,  1,  2,  3); q = s0[1]; STG4(q,  4,  5,  6,  7);
        q = s0[2]; STG4(q,  8,  9, 10, 11); q = s0[3]; STG4(q, 12, 13, 14, 15);
        q = s1[0]; STG4(q, 16, 17, 18, 19); q = s1[1]; STG4(q, 20, 21, 22, 23);
        q = s1[2]; STG4(q, 24, 25, 26, 27); q = s1[3]; STG4(q, 28, 29, 30, 31);
        q = s2[0]; STG4(q, 32, 33, 34, 35); q = s2[1]; STG4(q, 36, 37, 38, 39);
        q = s2[2]; STG4(q, 40, 41, 42, 43); q = s2[3]; STG4(q, 44, 45, 46, 47);
        q = s3[0]; STG4(q, 48, 49, 50, 51); q = s3[1]; STG4(q, 52, 53, 54, 55);
        q = s3[2]; STG4(q, 56, 57, 58, 59); q = s3[3]; STG4(q, 60, 61, 62, 63);
    }

    __shared__ alignas(16) unsigned short ph[2][L_];   // p (bf16), dbuf
    __shared__ float pj[L_ * 9];                       // partials, stride 9
    __shared__ float red[8];
    __shared__ float nmr[2];                           // sampled normalizer

    const bool owner = tid < L_;   // waves 0-3 own one state each
    const int m = tid;

    float s = 0.f, emit = 0.f, emit1 = 0.f;
    if (owner) s = yp[m];          // s_0 = y_pre[b,0,:]

    {   // exact initial max over 256 states (once)
        float v = owner ? s : -3.4e38f;
#pragma unroll
        for (int off = 1; off < 64; off <<= 1) v = fmaxf(v, __shfl_xor(v, off, 64));
        if (i == 0) red[c] = v;
        __syncthreads();
        if (tid == 0) {
            float M = fmaxf(fmaxf(red[0], red[1]), fmaxf(red[2], red[3]));
            nmr[0] = M; nmr[1] = M;
        }
        __syncthreads();
    }

    if (owner) {
        emit  = yp[(size_t)1 * L_ + m];   // E(1)
        emit1 = yp[(size_t)2 * L_ + m];   // E(2)
    }

    for (int t = 1; t < T_; ++t) {
        // ---- phase A (owners): normalize + publish p ----
        float N = 0.f, emit2 = 0.f;
        if (owner) {
            N = nmr[t & 1];                               // s_{t-2}[0] sample
            int tpf = (t + 2 <= T_ - 1) ? (t + 2) : (T_ - 1);
            emit2 = yp[(size_t)tpf * L_ + m];             // E(t+2)
            ph[t & 1][m] = f2bf(__expf(s - N));
        }
        __syncthreads();                   // barrier 1: p visible

        // ---- phase B (all 512): partial dots over own 32-l-chunk ----
        const uint4* P = ((const uint4*)&ph[t & 1][0]) + (c << 2);
        float a0=0,a1=0,a2=0,a3=0,b0=0,b1=0,b2=0,b3=0;
        {
            uint4 Pv = P[0];
            DOT4(Pv, a0, b0,  0,  1,  2,  3)
            DOT4(Pv, a1, b1, 16, 17, 18, 19)
            DOT4(Pv, a2, b2, 32, 33, 34, 35)
            DOT4(Pv, a3, b3, 48, 49, 50, 51)
        }
        {
            uint4 Pv = P[1];
            DOT4(Pv, a0, b0,  4,  5,  6,  7)
            DOT4(Pv, a1, b1, 20, 21, 22, 23)
            DOT4(Pv, a2, b2, 36, 37, 38, 39)
            DOT4(Pv, a3, b3, 52, 53, 54, 55)
        }
        {
            uint4 Pv = P[2];
            DOT4(Pv, a0, b0,  8,  9, 10, 11)
            DOT4(Pv, a1, b1, 24, 25, 26, 27)
            DOT4(Pv, a2, b2, 40, 41, 42, 43)
            DOT4(Pv, a3, b3, 56, 57, 58, 59)
        }
        {
            uint4 Pv = P[3];
            DOT4(Pv, a0, b0, 12, 13, 14, 15)
            DOT4(Pv, a1, b1, 28, 29, 30, 31)
            DOT4(Pv, a2, b2, 44, 45, 46, 47)
            DOT4(Pv, a3, b3, 60, 61, 62, 63)
        }
        pj[(i      ) * 9 + c] = a0 + b0;
        pj[(i +  64) * 9 + c] = a1 + b1;
        pj[(i + 128) * 9 + c] = a2 + b2;
        pj[(i + 192) * 9 + c] = a3 + b3;
        __syncthreads();                   // barrier 2: partials visible

        // ---- phase C (owners): combine 8 partials, advance state ----
        if (owner) {
            const float* q = &pj[m * 9];
            float sum = ((q[0] + q[1]) + (q[2] + q[3]))
                      + ((q[4] + q[5]) + (q[6] + q[7]));
            s = N + __logf(sum) + emit;
            emit = emit1; emit1 = emit2;
            if (tid == 0) nmr[t & 1] = s;  // sample for step t+2
        }
    }

    // ---- final logsumexp over m ----
    __syncthreads();
    {
        float v = owner ? s : -3.4e38f;
#pragma unroll
        for (int off = 1; off < 64; off <<= 1) v = fmaxf(v, __shfl_xor(v, off, 64));
        if (i == 0) red[c] = v;
    }
    __syncthreads();
    float M = fmaxf(fmaxf(red[0], red[1]), fmaxf(red[2], red[3]));
    float e = owner ? __expf(s - M) : 0.f;
    float v = e;
#pragma unroll
    for (int off = 1; off < 64; off <<= 1) v += __shfl_xor(v, off, 64);
    __syncthreads();   // protect red[] reuse
    if (i == 0) red[c] = v;
    __syncthreads();
    if (tid == 0)
        out[b] = M + __logf((red[0] + red[1]) + (red[2] + red[3])) - path[b];
}

// ---------------------------------------------------------------------------
extern "C" void kernel_launch(void* const* d_in, const int* in_sizes, int n_in,
                              void* d_out, int out_size, void* d_ws, size_t ws_size,
                              hipStream_t stream) {
    const float* y_true = (const float*)d_in[0];
    const float* y_pre  = (const float*)d_in[1];
    const float* trans  = (const float*)d_in[2];
    float* out = (float*)d_out;

    char* ws = (char*)d_ws;
    unsigned short* ETg = (unsigned short*)ws;            // 128 KiB
    int* labels = (int*)(ws + 131072);                    // 256 KiB
    float* path = (float*)(ws + 131072 + 262144);         // 512 B

    hipLaunchKernelGGL(k_exptrans, dim3(L_), dim3(L_), 0, stream, trans, ETg);
    hipLaunchKernelGGL(k_labels, dim3(B_ * T_ / 4), dim3(256), 0, stream, y_true, labels);
    hipLaunchKernelGGL(k_path, dim3(B_), dim3(256), 0, stream, y_pre, trans, labels, path);
    hipLaunchKernelGGL(k_forward, dim3(B_), dim3(512), 0, stream, y_pre, ETg, path, out);
}

// Round 10
// 364.647 us; speedup vs baseline: 1.2673x; 1.2673x over previous
//
#include <hip/hip_runtime.h>
#include <hip/hip_bf16.h>

#define B_ 128
#define T_ 512
#define L_ 256

typedef float f32x4 __attribute__((ext_vector_type(4)));
typedef unsigned uint32x4 __attribute__((ext_vector_type(4)));

__device__ __forceinline__ unsigned short f2bf(float x) {  // RNE f32->bf16
    unsigned u = __builtin_bit_cast(unsigned, x);
    return (unsigned short)((u + 0x7fff + ((u >> 16) & 1)) >> 16);
}

// Physical-AGPR staging (round-9-proven mechanism; regalloc cannot touch).
#define AW(n, v) asm volatile("v_accvgpr_write_b32 a" #n ", %0" :: "v"(v) : "a" #n)
#define STGF(F, A0, A1, A2, A3) { uint32x4 q = etb4[vbase + F * 64]; \
    AW(A0, q[0]); AW(A1, q[1]); AW(A2, q[2]); AW(A3, q[3]); }

// MFMA with B operand in hard-coded physical AGPRs (gfx950 unified RF).
// volatile: keeps program order w.r.t. the volatile staging writes above.
#define MFMA_AB(ACC, AF, LO, HI) \
    asm volatile("v_mfma_f32_16x16x32_bf16 %0, %1, a[" #LO ":" #HI "], %0" \
                 : "+v"(ACC) : "v"(AF))

// ---------------------------------------------------------------------------
// Kernel A: ETB = bf16(exp(trans)) pre-packed in MFMA B-fragment order.
// Frag block (w,nt,kt) = 1024 B at ((w*4+nt)*8+kt)*1024; within it lane
// (g*16+c) reads 16 B; dword d holds k-slots (g,2d),(g,2d+1) for col c:
// l = kt*32+g*8+i, m = 64w+nt*16+c. Self-consistent with A packing below.
// ---------------------------------------------------------------------------
__global__ __launch_bounds__(256) void k_exptrans(const float* __restrict__ trans,
                                                  unsigned short* __restrict__ ETB) {
    int l = blockIdx.x;          // 256 blocks = rows of trans
    int m = threadIdx.x;         // 256 threads = cols
    unsigned short v = f2bf(__expf(trans[l * L_ + m]));
    unsigned byte = (unsigned)((m >> 4) * 8 + (l >> 5)) * 1024u
                  + (unsigned)(((l >> 3) & 3) * 16 + (m & 15)) * 16u
                  + (unsigned)(((l >> 1) & 3)) * 4u + (unsigned)(l & 1) * 2u;
    *(unsigned short*)((char*)ETB + byte) = v;
}

// ---------------------------------------------------------------------------
// Kernel B: labels from one-hot y_true (one wave per row)
// ---------------------------------------------------------------------------
__global__ __launch_bounds__(256) void k_labels(const float* __restrict__ y_true,
                                                int* __restrict__ labels) {
    int wid = threadIdx.x >> 6, lane = threadIdx.x & 63;
    int r = blockIdx.x * 4 + wid;
    const float4* row = (const float4*)(y_true + (size_t)r * L_);
    float4 v = row[lane];
    int loc = -1;
    if (v.x > 0.5f) loc = lane * 4 + 0;
    if (v.y > 0.5f) loc = lane * 4 + 1;
    if (v.z > 0.5f) loc = lane * 4 + 2;
    if (v.w > 0.5f) loc = lane * 4 + 3;
    unsigned long long m = __ballot(loc >= 0);
    int src = __ffsll(m) - 1;
    int lab = __shfl(loc, src, 64);
    if (lane == 0) labels[r] = lab;
}

// ---------------------------------------------------------------------------
// Kernel C: path_score
// ---------------------------------------------------------------------------
__global__ __launch_bounds__(256) void k_path(const float* __restrict__ y_pre,
                                              const float* __restrict__ trans,
                                              const int* __restrict__ labels,
                                              float* __restrict__ path) {
    int b = blockIdx.x, tid = threadIdx.x;
    const int* lb = labels + b * T_;
    float acc = 0.f;
    for (int t = tid; t < T_; t += 256) {
        int l1 = lb[t];
        acc += y_pre[((size_t)b * T_ + t) * L_ + l1];
        if (t + 1 < T_) acc += trans[l1 * L_ + lb[t + 1]];
    }
#pragma unroll
    for (int off = 1; off < 64; off <<= 1) acc += __shfl_xor(acc, off, 64);
    __shared__ float red[4];
    int wid = tid >> 6, lane = tid & 63;
    if (lane == 0) red[wid] = acc;
    __syncthreads();
    if (tid == 0) path[b] = red[0] + red[1] + red[2] + red[3];
}

// ---------------------------------------------------------------------------
// Kernel D: forward recursion via MFMA. 1 chain/block, 4 waves, 128 blocks.
// Rounds 2-9 post-mortem: distributing the 512-B p-vector by uniform LDS
// broadcast reads costs ~12cyc/16-useful-bytes -> 1500+ cyc/step, and that
// (not ET residency) was the bottleneck. MFMA does the cross-state reduction
// in the matrix pipe: A = p (row 0; rows duplicate), B = exp(trans) staged
// ONCE in physical AGPRs a0..a127/wave (zero per-step cost, unspillable).
// Per step: 8 ds_read_b128/wave + 32 MFMA/wave + owner log/exp + ONE barrier.
// Slot-bijection: A and B packed with the same k-slot convention -> correct
// for any HW k-permutation; D layout HW-verified (m89): row0 = lanes 0-15
// reg 0. Normalizer: lag-1 sample s_{t-1}[0] (race-free, 2-slot).
// ---------------------------------------------------------------------------
__global__ void __launch_bounds__(256, 1)
k_forward(const float* __restrict__ yp_all,
          const unsigned short* __restrict__ ETB,
          const float* __restrict__ path,
          float* __restrict__ out) {
    int b = blockIdx.x, tid = threadIdx.x;
    int w = tid >> 6;            // wave: owns states [64w, 64w+64)
    int i = tid & 63;            // lane
    int g = i >> 4;              // k-group within fragments
    const float* yp = yp_all + (size_t)b * T_ * L_;

    // ---- stage B-fragments (32 x 16B) into physical a0..a127 ----
    {
        const uint32x4* etb4 = (const uint32x4*)ETB;
        int vbase = w * 2048 + i;
        STGF( 0,   0,  1,  2,  3)  STGF( 1,   4,  5,  6,  7)
        STGF( 2,   8,  9, 10, 11)  STGF( 3,  12, 13, 14, 15)
        STGF( 4,  16, 17, 18, 19)  STGF( 5,  20, 21, 22, 23)
        STGF( 6,  24, 25, 26, 27)  STGF( 7,  28, 29, 30, 31)
        STGF( 8,  32, 33, 34, 35)  STGF( 9,  36, 37, 38, 39)
        STGF(10,  40, 41, 42, 43)  STGF(11,  44, 45, 46, 47)
        STGF(12,  48, 49, 50, 51)  STGF(13,  52, 53, 54, 55)
        STGF(14,  56, 57, 58, 59)  STGF(15,  60, 61, 62, 63)
        STGF(16,  64, 65, 66, 67)  STGF(17,  68, 69, 70, 71)
        STGF(18,  72, 73, 74, 75)  STGF(19,  76, 77, 78, 79)
        STGF(20,  80, 81, 82, 83)  STGF(21,  84, 85, 86, 87)
        STGF(22,  88, 89, 90, 91)  STGF(23,  92, 93, 94, 95)
        STGF(24,  96, 97, 98, 99)  STGF(25, 100,101,102,103)
        STGF(26, 104,105,106,107)  STGF(27, 108,109,110,111)
        STGF(28, 112,113,114,115)  STGF(29, 116,117,118,119)
        STGF(30, 120,121,122,123)  STGF(31, 124,125,126,127)
    }

    __shared__ alignas(16) unsigned short ph[2][L_];  // p (bf16), dbuf
    __shared__ float red[8];
    __shared__ float nmr[2];

    const bool owner = (i < 16);
    const int m0 = (w << 6) + i;          // owner states: m0, +16, +32, +48

    // ---- init: s0, exact max M0, p0 ----
    float s0n = 0.f, s1n = 0.f, s2n = 0.f, s3n = 0.f;
    if (owner) {
        s0n = yp[m0]; s1n = yp[m0 + 16]; s2n = yp[m0 + 32]; s3n = yp[m0 + 48];
    }
    {
        float v = owner ? fmaxf(fmaxf(s0n, s1n), fmaxf(s2n, s3n)) : -3.4e38f;
#pragma unroll
        for (int off = 1; off < 64; off <<= 1) v = fmaxf(v, __shfl_xor(v, off, 64));
        if (i == 0) red[w] = v;
        __syncthreads();
        if (tid == 0) {
            float M = fmaxf(fmaxf(red[0], red[1]), fmaxf(red[2], red[3]));
            nmr[0] = M; nmr[1] = M;
        }
        __syncthreads();
    }
    float N_prev = fmaxf(fmaxf(red[0], red[1]), fmaxf(red[2], red[3]));
    if (owner) {
        unsigned short* pw = ph[1];
        pw[m0]      = f2bf(__expf(s0n - N_prev));
        pw[m0 + 16] = f2bf(__expf(s1n - N_prev));
        pw[m0 + 32] = f2bf(__expf(s2n - N_prev));
        pw[m0 + 48] = f2bf(__expf(s3n - N_prev));
    }

    // emit prefetch, 3 deep: eA=E(t), eB=E(t+1), eC=E(t+2)
    float eA0=0,eA1=0,eA2=0,eA3=0, eB0=0,eB1=0,eB2=0,eB3=0, eC0=0,eC1=0,eC2=0,eC3=0;
    if (owner) {
        const float* y1 = yp + L_;
        eA0 = y1[m0]; eA1 = y1[m0+16]; eA2 = y1[m0+32]; eA3 = y1[m0+48];
        const float* y2 = yp + 2 * L_;
        eB0 = y2[m0]; eB1 = y2[m0+16]; eB2 = y2[m0+32]; eB3 = y2[m0+48];
        const float* y3 = yp + 3 * L_;
        eC0 = y3[m0]; eC1 = y3[m0+16]; eC2 = y3[m0+32]; eC3 = y3[m0+48];
    }
    __syncthreads();   // p0 + nmr visible

    for (int t = 1; t < T_; ++t) {
        // ---- A-fragments from ph[t&1] (4 distinct 16B per wave-op) ----
        const uint32x4* pA = (const uint32x4*)ph[t & 1];
        uint32x4 af0 = pA[g];      uint32x4 af1 = pA[g + 4];
        uint32x4 af2 = pA[g + 8];  uint32x4 af3 = pA[g + 12];
        uint32x4 af4 = pA[g + 16]; uint32x4 af5 = pA[g + 20];
        uint32x4 af6 = pA[g + 24]; uint32x4 af7 = pA[g + 28];

        f32x4 c0 = {0.f,0.f,0.f,0.f}, c1 = {0.f,0.f,0.f,0.f};
        f32x4 c2 = {0.f,0.f,0.f,0.f}, c3 = {0.f,0.f,0.f,0.f};
        MFMA_AB(c0, af0,   0,   3); MFMA_AB(c1, af0,  32,  35);
        MFMA_AB(c2, af0,  64,  67); MFMA_AB(c3, af0,  96,  99);
        MFMA_AB(c0, af1,   4,   7); MFMA_AB(c1, af1,  36,  39);
        MFMA_AB(c2, af1,  68,  71); MFMA_AB(c3, af1, 100, 103);
        MFMA_AB(c0, af2,   8,  11); MFMA_AB(c1, af2,  40,  43);
        MFMA_AB(c2, af2,  72,  75); MFMA_AB(c3, af2, 104, 107);
        MFMA_AB(c0, af3,  12,  15); MFMA_AB(c1, af3,  44,  47);
        MFMA_AB(c2, af3,  76,  79); MFMA_AB(c3, af3, 108, 111);
        MFMA_AB(c0, af4,  16,  19); MFMA_AB(c1, af4,  48,  51);
        MFMA_AB(c2, af4,  80,  83); MFMA_AB(c3, af4, 112, 115);
        MFMA_AB(c0, af5,  20,  23); MFMA_AB(c1, af5,  52,  55);
        MFMA_AB(c2, af5,  84,  87); MFMA_AB(c3, af5, 116, 119);
        MFMA_AB(c0, af6,  24,  27); MFMA_AB(c1, af6,  56,  59);
        MFMA_AB(c2, af6,  88,  91); MFMA_AB(c3, af6, 120, 123);
        MFMA_AB(c0, af7,  28,  31); MFMA_AB(c1, af7,  60,  63);
        MFMA_AB(c2, af7,  92,  95); MFMA_AB(c3, af7, 124, 127);

        // ---- owner phase: s_t = N_prev + log(acc) + E(t); p_t -> ph ----
        if (owner) {
            s0n = N_prev + __logf(c0[0]) + eA0;
            s1n = N_prev + __logf(c1[0]) + eA1;
            s2n = N_prev + __logf(c2[0]) + eA2;
            s3n = N_prev + __logf(c3[0]) + eA3;
            if (tid == 0) nmr[t & 1] = s0n;          // for step t+1
            float N_cur = nmr[(t + 1) & 1];           // = s_{t-1}[0]
            unsigned short* pw = ph[(t + 1) & 1];
            pw[m0]      = f2bf(__expf(s0n - N_cur));
            pw[m0 + 16] = f2bf(__expf(s1n - N_cur));
            pw[m0 + 32] = f2bf(__expf(s2n - N_cur));
            pw[m0 + 48] = f2bf(__expf(s3n - N_cur));
            N_prev = N_cur;
            // rotate emit pipeline; prefetch E(t+3)
            eA0 = eB0; eA1 = eB1; eA2 = eB2; eA3 = eB3;
            eB0 = eC0; eB1 = eC1; eB2 = eC2; eB3 = eC3;
            int tp = (t + 3 <= T_ - 1) ? (t + 3) : (T_ - 1);
            const float* yn = yp + (size_t)tp * L_;
            eC0 = yn[m0]; eC1 = yn[m0+16]; eC2 = yn[m0+32]; eC3 = yn[m0+48];
        }
        __syncthreads();   // ONE barrier/step: p_t + nmr visible
    }

    // ---- final logsumexp over m ----
    {
        float v = owner ? fmaxf(fmaxf(s0n, s1n), fmaxf(s2n, s3n)) : -3.4e38f;
#pragma unroll
        for (int off = 1; off < 64; off <<= 1) v = fmaxf(v, __shfl_xor(v, off, 64));
        if (i == 0) red[w] = v;
    }
    __syncthreads();
    float M = fmaxf(fmaxf(red[0], red[1]), fmaxf(red[2], red[3]));
    float e = owner ? (__expf(s0n - M) + __expf(s1n - M) +
                       __expf(s2n - M) + __expf(s3n - M)) : 0.f;
#pragma unroll
    for (int off = 1; off < 64; off <<= 1) e += __shfl_xor(e, off, 64);
    if (i == 0) red[4 + w] = e;
    __syncthreads();
    if (tid == 0)
        out[b] = M + __logf((red[4] + red[5]) + (red[6] + red[7])) - path[b];
}

// ---------------------------------------------------------------------------
extern "C" void kernel_launch(void* const* d_in, const int* in_sizes, int n_in,
                              void* d_out, int out_size, void* d_ws, size_t ws_size,
                              hipStream_t stream) {
    const float* y_true = (const float*)d_in[0];
    const float* y_pre  = (const float*)d_in[1];
    const float* trans  = (const float*)d_in[2];
    float* out = (float*)d_out;

    char* ws = (char*)d_ws;
    unsigned short* ETB = (unsigned short*)ws;            // 128 KiB (frag order)
    int* labels = (int*)(ws + 131072);                    // 256 KiB
    float* path = (float*)(ws + 131072 + 262144);         // 512 B

    hipLaunchKernelGGL(k_exptrans, dim3(L_), dim3(L_), 0, stream, trans, ETB);
    hipLaunchKernelGGL(k_labels, dim3(B_ * T_ / 4), dim3(256), 0, stream, y_true, labels);
    hipLaunchKernelGGL(k_path, dim3(B_), dim3(256), 0, stream, y_pre, trans, labels, path);
    hipLaunchKernelGGL(k_forward, dim3(B_), dim3(256), 0, stream, y_pre, ETB, path, out);
}

// Round 12
// 319.665 us; speedup vs baseline: 1.4456x; 1.1407x over previous
//
#include <hip/hip_runtime.h>
#include <hip/hip_bf16.h>

#define B_ 128
#define T_ 512
#define L_ 256

typedef float f32x4 __attribute__((ext_vector_type(4)));
typedef unsigned uint32x4 __attribute__((ext_vector_type(4)));

__device__ __forceinline__ unsigned short f2bf(float x) {  // RNE f32->bf16
    unsigned u = __builtin_bit_cast(unsigned, x);
    return (unsigned short)((u + 0x7fff + ((u >> 16) & 1)) >> 16);
}

// Physical-AGPR staging (round-9/10-proven; regalloc cannot touch).
#define AW(n, v) asm volatile("v_accvgpr_write_b32 a" #n ", %0" :: "v"(v) : "a" #n)
#define STGF(F, A0, A1, A2, A3) { uint32x4 q = etb4[vbase + F * 64]; \
    AW(A0, q[0]); AW(A1, q[1]); AW(A2, q[2]); AW(A3, q[3]); }

// MFMA with B operand in hard-coded physical AGPRs (gfx950 unified RF).
#define MFMA_AB(ACC, AF, LO, HI) \
    asm volatile("v_mfma_f32_16x16x32_bf16 %0, %1, a[" #LO ":" #HI "], %0" \
                 : "+v"(ACC) : "v"(AF))

// ---------------------------------------------------------------------------
// Kernel A: ETB = bf16(exp(trans)) pre-packed in MFMA B-fragment order.
// (unchanged from round 10 — HW-verified by round-10 absmax 0.0)
// ---------------------------------------------------------------------------
__global__ __launch_bounds__(256) void k_exptrans(const float* __restrict__ trans,
                                                  unsigned short* __restrict__ ETB) {
    int l = blockIdx.x;          // 256 blocks = rows of trans
    int m = threadIdx.x;         // 256 threads = cols
    unsigned short v = f2bf(__expf(trans[l * L_ + m]));
    unsigned byte = (unsigned)((m >> 4) * 8 + (l >> 5)) * 1024u
                  + (unsigned)(((l >> 3) & 3) * 16 + (m & 15)) * 16u
                  + (unsigned)(((l >> 1) & 3)) * 4u + (unsigned)(l & 1) * 2u;
    *(unsigned short*)((char*)ETB + byte) = v;
}

// ---------------------------------------------------------------------------
// Kernel B: labels from one-hot y_true (one wave per row)
// ---------------------------------------------------------------------------
__global__ __launch_bounds__(256) void k_labels(const float* __restrict__ y_true,
                                                int* __restrict__ labels) {
    int wid = threadIdx.x >> 6, lane = threadIdx.x & 63;
    int r = blockIdx.x * 4 + wid;
    const float4* row = (const float4*)(y_true + (size_t)r * L_);
    float4 v = row[lane];
    int loc = -1;
    if (v.x > 0.5f) loc = lane * 4 + 0;
    if (v.y > 0.5f) loc = lane * 4 + 1;
    if (v.z > 0.5f) loc = lane * 4 + 2;
    if (v.w > 0.5f) loc = lane * 4 + 3;
    unsigned long long m = __ballot(loc >= 0);
    int src = __ffsll(m) - 1;
    int lab = __shfl(loc, src, 64);
    if (lane == 0) labels[r] = lab;
}

// ---------------------------------------------------------------------------
// Kernel C: path_score
// ---------------------------------------------------------------------------
__global__ __launch_bounds__(256) void k_path(const float* __restrict__ y_pre,
                                              const float* __restrict__ trans,
                                              const int* __restrict__ labels,
                                              float* __restrict__ path) {
    int b = blockIdx.x, tid = threadIdx.x;
    const int* lb = labels + b * T_;
    float acc = 0.f;
    for (int t = tid; t < T_; t += 256) {
        int l1 = lb[t];
        acc += y_pre[((size_t)b * T_ + t) * L_ + l1];
        if (t + 1 < T_) acc += trans[l1 * L_ + lb[t + 1]];
    }
#pragma unroll
    for (int off = 1; off < 64; off <<= 1) acc += __shfl_xor(acc, off, 64);
    __shared__ float red[4];
    int wid = tid >> 6, lane = tid & 63;
    if (lane == 0) red[wid] = acc;
    __syncthreads();
    if (tid == 0) path[b] = red[0] + red[1] + red[2] + red[3];
}

// ---------------------------------------------------------------------------
// Kernel D: forward recursion via MFMA — round-10 structure (PASSING, 4 waves,
// B in a0..a127) + ALL-LANE finish only (bisection arm 1 of round 11).
// D's rows are identical (all 16 lanes of a lane-group carry the same A
// bytes), so lane i's c_g[0] (g=i>>4) holds the result for state st=64w+i:
// every lane does 1 log + 1 exp and writes its own p (was: 16 owner lanes
// x 4 serial). All other logic (lag-1 normalizer protocol, MFMA chains,
// staging, packing) is bit-identical to round 10.
// ---------------------------------------------------------------------------
__global__ void __launch_bounds__(256, 1)
k_forward(const float* __restrict__ yp_all,
          const unsigned short* __restrict__ ETB,
          const float* __restrict__ path,
          float* __restrict__ out) {
    int b = blockIdx.x, tid = threadIdx.x;
    int w = tid >> 6;            // wave: owns states [64w, 64w+64)
    int i = tid & 63;            // lane
    int g = i >> 4;              // lane group 0..3
    const int st = (w << 6) + i; // this lane's state
    const float* yp = yp_all + (size_t)b * T_ * L_;

    // ---- stage B-fragments (32 x 16B) into physical a0..a127 ----
    {
        const uint32x4* etb4 = (const uint32x4*)ETB;
        int vbase = w * 2048 + i;
        STGF( 0,   0,  1,  2,  3)  STGF( 1,   4,  5,  6,  7)
        STGF( 2,   8,  9, 10, 11)  STGF( 3,  12, 13, 14, 15)
        STGF( 4,  16, 17, 18, 19)  STGF( 5,  20, 21, 22, 23)
        STGF( 6,  24, 25, 26, 27)  STGF( 7,  28, 29, 30, 31)
        STGF( 8,  32, 33, 34, 35)  STGF( 9,  36, 37, 38, 39)
        STGF(10,  40, 41, 42, 43)  STGF(11,  44, 45, 46, 47)
        STGF(12,  48, 49, 50, 51)  STGF(13,  52, 53, 54, 55)
        STGF(14,  56, 57, 58, 59)  STGF(15,  60, 61, 62, 63)
        STGF(16,  64, 65, 66, 67)  STGF(17,  68, 69, 70, 71)
        STGF(18,  72, 73, 74, 75)  STGF(19,  76, 77, 78, 79)
        STGF(20,  80, 81, 82, 83)  STGF(21,  84, 85, 86, 87)
        STGF(22,  88, 89, 90, 91)  STGF(23,  92, 93, 94, 95)
        STGF(24,  96, 97, 98, 99)  STGF(25, 100,101,102,103)
        STGF(26, 104,105,106,107)  STGF(27, 108,109,110,111)
        STGF(28, 112,113,114,115)  STGF(29, 116,117,118,119)
        STGF(30, 120,121,122,123)  STGF(31, 124,125,126,127)
    }

    __shared__ alignas(16) unsigned short ph[2][L_];  // p (bf16), dbuf
    __shared__ float red[8];
    __shared__ float nmr[2];

    // ---- init: s0, exact max M0, p0 ----
    float s = yp[st];
    {
        float v = s;
#pragma unroll
        for (int off = 1; off < 64; off <<= 1) v = fmaxf(v, __shfl_xor(v, off, 64));
        if (i == 0) red[w] = v;
        __syncthreads();
        if (tid == 0) {
            float M = fmaxf(fmaxf(red[0], red[1]), fmaxf(red[2], red[3]));
            nmr[0] = M; nmr[1] = M;
        }
        __syncthreads();
    }
    float N_prev = nmr[0];
    ph[1][st] = f2bf(__expf(s - N_prev));

    // emit prefetch, 3 deep (1 float/lane/step; coalesced: st = 64w+i)
    float eA = yp[(size_t)1 * L_ + st];
    float eB = yp[(size_t)2 * L_ + st];
    float eC = yp[(size_t)3 * L_ + st];
    __syncthreads();   // p0 visible

    for (int t = 1; t < T_; ++t) {
        // ---- A-fragments from ph[t&1] (identical to round 10) ----
        const uint32x4* pA = (const uint32x4*)ph[t & 1];
        uint32x4 af0 = pA[g];      uint32x4 af1 = pA[g + 4];
        uint32x4 af2 = pA[g + 8];  uint32x4 af3 = pA[g + 12];
        uint32x4 af4 = pA[g + 16]; uint32x4 af5 = pA[g + 20];
        uint32x4 af6 = pA[g + 24]; uint32x4 af7 = pA[g + 28];

        f32x4 c0 = {0.f,0.f,0.f,0.f}, c1 = {0.f,0.f,0.f,0.f};
        f32x4 c2 = {0.f,0.f,0.f,0.f}, c3 = {0.f,0.f,0.f,0.f};
        MFMA_AB(c0, af0,   0,   3); MFMA_AB(c1, af0,  32,  35);
        MFMA_AB(c2, af0,  64,  67); MFMA_AB(c3, af0,  96,  99);
        MFMA_AB(c0, af1,   4,   7); MFMA_AB(c1, af1,  36,  39);
        MFMA_AB(c2, af1,  68,  71); MFMA_AB(c3, af1, 100, 103);
        MFMA_AB(c0, af2,   8,  11); MFMA_AB(c1, af2,  40,  43);
        MFMA_AB(c2, af2,  72,  75); MFMA_AB(c3, af2, 104, 107);
        MFMA_AB(c0, af3,  12,  15); MFMA_AB(c1, af3,  44,  47);
        MFMA_AB(c2, af3,  76,  79); MFMA_AB(c3, af3, 108, 111);
        MFMA_AB(c0, af4,  16,  19); MFMA_AB(c1, af4,  48,  51);
        MFMA_AB(c2, af4,  80,  83); MFMA_AB(c3, af4, 112, 115);
        MFMA_AB(c0, af5,  20,  23); MFMA_AB(c1, af5,  52,  55);
        MFMA_AB(c2, af5,  84,  87); MFMA_AB(c3, af5, 116, 119);
        MFMA_AB(c0, af6,  24,  27); MFMA_AB(c1, af6,  56,  59);
        MFMA_AB(c2, af6,  88,  91); MFMA_AB(c3, af6, 120, 123);
        MFMA_AB(c0, af7,  28,  31); MFMA_AB(c1, af7,  60,  63);
        MFMA_AB(c2, af7,  92,  95); MFMA_AB(c3, af7, 124, 127);

        // ---- ALL-lane finish: 1 log + 1 exp per lane ----
        float val = (g < 2) ? ((g == 0) ? c0[0] : c1[0])
                            : ((g == 2) ? c2[0] : c3[0]);
        s = N_prev + __logf(val) + eA;
        if (tid == 0) nmr[t & 1] = s;          // sample s_t[0] for step t+1
        float N_cur = nmr[(t + 1) & 1];        // = s_{t-1}[0]
        ph[(t + 1) & 1][st] = f2bf(__expf(s - N_cur));
        N_prev = N_cur;
        eA = eB; eB = eC;
        int tp = (t + 3 <= T_ - 1) ? (t + 3) : (T_ - 1);
        eC = yp[(size_t)tp * L_ + st];
        __syncthreads();   // ONE barrier/step: p_t + nmr visible
    }

    // ---- final logsumexp over states (all lanes hold unique st) ----
    {
        float v = s;
#pragma unroll
        for (int off = 1; off < 64; off <<= 1) v = fmaxf(v, __shfl_xor(v, off, 64));
        if (i == 0) red[w] = v;
    }
    __syncthreads();
    float M = fmaxf(fmaxf(red[0], red[1]), fmaxf(red[2], red[3]));
    float e = __expf(s - M);
#pragma unroll
    for (int off = 1; off < 64; off <<= 1) e += __shfl_xor(e, off, 64);
    if (i == 0) red[4 + w] = e;
    __syncthreads();
    if (tid == 0)
        out[b] = M + __logf((red[4] + red[5]) + (red[6] + red[7])) - path[b];
}

// ---------------------------------------------------------------------------
extern "C" void kernel_launch(void* const* d_in, const int* in_sizes, int n_in,
                              void* d_out, int out_size, void* d_ws, size_t ws_size,
                              hipStream_t stream) {
    const float* y_true = (const float*)d_in[0];
    const float* y_pre  = (const float*)d_in[1];
    const float* trans  = (const float*)d_in[2];
    float* out = (float*)d_out;

    char* ws = (char*)d_ws;
    unsigned short* ETB = (unsigned short*)ws;            // 128 KiB (frag order)
    int* labels = (int*)(ws + 131072);                    // 256 KiB
    float* path = (float*)(ws + 131072 + 262144);         // 512 B

    hipLaunchKernelGGL(k_exptrans, dim3(L_), dim3(L_), 0, stream, trans, ETB);
    hipLaunchKernelGGL(k_labels, dim3(B_ * T_ / 4), dim3(256), 0, stream, y_true, labels);
    hipLaunchKernelGGL(k_path, dim3(B_), dim3(256), 0, stream, y_pre, trans, labels, path);
    hipLaunchKernelGGL(k_forward, dim3(B_), dim3(256), 0, stream, y_pre, ETB, path, out);
}

// Round 14
// 245.345 us; speedup vs baseline: 1.8835x; 1.3029x over previous
//
#include <hip/hip_runtime.h>
#include <hip/hip_bf16.h>

#define B_ 128
#define T_ 512
#define L_ 256

typedef float f32x4 __attribute__((ext_vector_type(4)));
typedef unsigned uint32x4 __attribute__((ext_vector_type(4)));

__device__ __forceinline__ unsigned short f2bf(float x) {  // RNE f32->bf16
    unsigned u = __builtin_bit_cast(unsigned, x);
    return (unsigned short)((u + 0x7fff + ((u >> 16) & 1)) >> 16);
}

// Physical-AGPR staging (round-9/10-proven; regalloc cannot touch).
#define AW(n, v) asm volatile("v_accvgpr_write_b32 a" #n ", %0" :: "v"(v) : "a" #n)
#define STGF(F, A0, A1, A2, A3) { uint32x4 qq = etb4[vbase + F * 64]; \
    AW(A0, qq[0]); AW(A1, qq[1]); AW(A2, qq[2]); AW(A3, qq[3]); }

// MFMA with B operand in hard-coded physical AGPRs (gfx950 unified RF).
#define MFMA_AB(ACC, AF, LO, HI) \
    asm volatile("v_mfma_f32_16x16x32_bf16 %0, %1, a[" #LO ":" #HI "], %0" \
                 : "+v"(ACC) : "v"(AF))

// ---------------------------------------------------------------------------
// Kernel A: ETB = bf16(exp(trans)) pre-packed in MFMA B-fragment order.
// (unchanged — HW-verified by round-10 absmax 0.0)
// ---------------------------------------------------------------------------
__global__ __launch_bounds__(256) void k_exptrans(const float* __restrict__ trans,
                                                  unsigned short* __restrict__ ETB) {
    int l = blockIdx.x;          // 256 blocks = rows of trans
    int m = threadIdx.x;         // 256 threads = cols
    unsigned short v = f2bf(__expf(trans[l * L_ + m]));
    unsigned byte = (unsigned)((m >> 4) * 8 + (l >> 5)) * 1024u
                  + (unsigned)(((l >> 3) & 3) * 16 + (m & 15)) * 16u
                  + (unsigned)(((l >> 1) & 3)) * 4u + (unsigned)(l & 1) * 2u;
    *(unsigned short*)((char*)ETB + byte) = v;
}

// ---------------------------------------------------------------------------
// Kernel B: labels from one-hot y_true (one wave per row)
// ---------------------------------------------------------------------------
__global__ __launch_bounds__(256) void k_labels(const float* __restrict__ y_true,
                                                int* __restrict__ labels) {
    int wid = threadIdx.x >> 6, lane = threadIdx.x & 63;
    int r = blockIdx.x * 4 + wid;
    const float4* row = (const float4*)(y_true + (size_t)r * L_);
    float4 v = row[lane];
    int loc = -1;
    if (v.x > 0.5f) loc = lane * 4 + 0;
    if (v.y > 0.5f) loc = lane * 4 + 1;
    if (v.z > 0.5f) loc = lane * 4 + 2;
    if (v.w > 0.5f) loc = lane * 4 + 3;
    unsigned long long m = __ballot(loc >= 0);
    int src = __ffsll(m) - 1;
    int lab = __shfl(loc, src, 64);
    if (lane == 0) labels[r] = lab;
}

// ---------------------------------------------------------------------------
// Kernel C: path_score
// ---------------------------------------------------------------------------
__global__ __launch_bounds__(256) void k_path(const float* __restrict__ y_pre,
                                              const float* __restrict__ trans,
                                              const int* __restrict__ labels,
                                              float* __restrict__ path) {
    int b = blockIdx.x, tid = threadIdx.x;
    const int* lb = labels + b * T_;
    float acc = 0.f;
    for (int t = tid; t < T_; t += 256) {
        int l1 = lb[t];
        acc += y_pre[((size_t)b * T_ + t) * L_ + l1];
        if (t + 1 < T_) acc += trans[l1 * L_ + lb[t + 1]];
    }
#pragma unroll
    for (int off = 1; off < 64; off <<= 1) acc += __shfl_xor(acc, off, 64);
    __shared__ float red[4];
    int wid = tid >> 6, lane = tid & 63;
    if (lane == 0) red[wid] = acc;
    __syncthreads();
    if (tid == 0) path[b] = red[0] + red[1] + red[2] + red[3];
}

// ---------------------------------------------------------------------------
// Kernel D: forward recursion via MFMA — round-12 wave structure (4 waves,
// PASSING), with the serial tail removed:
//  (1) p_t = val_t * exp(D_{t-1} + e_t - D_t)  [exact identity] — the scale
//      exp depends only on OLD data and runs in the VALU concurrently with
//      the MFMA section; post-MFMA path = select+mul+cvt+ds_write (~30cy).
//  (2) lag-2 normalizer D_t = s_{t-2}[0] in a 4-slot nmr ring — the D-read
//      at step top is 2 barriers old (zero exposed latency).
//  (3) 4x-unrolled t-loop, 4 named emit regs, use-then-reload (no register
//      copies) -> emit load distance = 4 steps (~2000cy) > HBM latency.
// s (with log) still computed per lane in the tail, but OFF the p-path —
// only lane0's nmr sample (consumed 2 steps later) and the final LSE use it.
// ---------------------------------------------------------------------------
#define MFMA32()                                                         \
        MFMA_AB(c0, af0,   0,   3); MFMA_AB(c1, af0,  32,  35);          \
        MFMA_AB(c2, af0,  64,  67); MFMA_AB(c3, af0,  96,  99);          \
        MFMA_AB(c0, af1,   4,   7); MFMA_AB(c1, af1,  36,  39);          \
        MFMA_AB(c2, af1,  68,  71); MFMA_AB(c3, af1, 100, 103);          \
        MFMA_AB(c0, af2,   8,  11); MFMA_AB(c1, af2,  40,  43);          \
        MFMA_AB(c2, af2,  72,  75); MFMA_AB(c3, af2, 104, 107);          \
        MFMA_AB(c0, af3,  12,  15); MFMA_AB(c1, af3,  44,  47);          \
        MFMA_AB(c2, af3,  76,  79); MFMA_AB(c3, af3, 108, 111);          \
        MFMA_AB(c0, af4,  16,  19); MFMA_AB(c1, af4,  48,  51);          \
        MFMA_AB(c2, af4,  80,  83); MFMA_AB(c3, af4, 112, 115);          \
        MFMA_AB(c0, af5,  20,  23); MFMA_AB(c1, af5,  52,  55);          \
        MFMA_AB(c2, af5,  84,  87); MFMA_AB(c3, af5, 116, 119);          \
        MFMA_AB(c0, af6,  24,  27); MFMA_AB(c1, af6,  56,  59);          \
        MFMA_AB(c2, af6,  88,  91); MFMA_AB(c3, af6, 120, 123);          \
        MFMA_AB(c0, af7,  28,  31); MFMA_AB(c1, af7,  60,  63);          \
        MFMA_AB(c2, af7,  92,  95); MFMA_AB(c3, af7, 124, 127);

#define STEP(TT, PH_RD, PH_WR, DSLOT, WSLOT, EREG)                       \
    {                                                                    \
        float Dt = nmr[DSLOT];              /* s_{t-2}[0], 2 barriers old */ \
        float scale = __expf(NPprev + EREG - Dt);  /* runs during MFMA */ \
        const uint32x4* pA = (const uint32x4*)ph[PH_RD];                 \
        uint32x4 af0 = pA[g];      uint32x4 af1 = pA[g + 4];             \
        uint32x4 af2 = pA[g + 8];  uint32x4 af3 = pA[g + 12];            \
        uint32x4 af4 = pA[g + 16]; uint32x4 af5 = pA[g + 20];            \
        uint32x4 af6 = pA[g + 24]; uint32x4 af7 = pA[g + 28];            \
        f32x4 c0 = {0.f,0.f,0.f,0.f}, c1 = {0.f,0.f,0.f,0.f};            \
        f32x4 c2 = {0.f,0.f,0.f,0.f}, c3 = {0.f,0.f,0.f,0.f};            \
        MFMA32()                                                         \
        float val = (g < 2) ? ((g == 0) ? c0[0] : c1[0])                 \
                            : ((g == 2) ? c2[0] : c3[0]);                \
        ph[PH_WR][st] = f2bf(val * scale);   /* p-path: mul+cvt+write */ \
        s = NPprev + __logf(val) + EREG;     /* off p-path */            \
        if (tid == 0) nmr[WSLOT] = s;        /* consumed at t+2 */       \
        NPprev = Dt;                                                     \
        { int tp = (TT) + 4; if (tp > T_ - 1) tp = T_ - 1;               \
          EREG = yp[(size_t)tp * L_ + st]; } /* reload, distance 4 */    \
        __syncthreads();                                                 \
    }

__global__ void __launch_bounds__(256, 1)
k_forward(const float* __restrict__ yp_all,
          const unsigned short* __restrict__ ETB,
          const float* __restrict__ path,
          float* __restrict__ out) {
    int b = blockIdx.x, tid = threadIdx.x;
    int w = tid >> 6;            // wave: owns states [64w, 64w+64)
    int i = tid & 63;            // lane
    int g = i >> 4;              // lane group 0..3
    const int st = (w << 6) + i; // this lane's state
    const float* yp = yp_all + (size_t)b * T_ * L_;

    // ---- stage B-fragments (32 x 16B) into physical a0..a127 ----
    {
        const uint32x4* etb4 = (const uint32x4*)ETB;
        int vbase = w * 2048 + i;
        STGF( 0,   0,  1,  2,  3)  STGF( 1,   4,  5,  6,  7)
        STGF( 2,   8,  9, 10, 11)  STGF( 3,  12, 13, 14, 15)
        STGF( 4,  16, 17, 18, 19)  STGF( 5,  20, 21, 22, 23)
        STGF( 6,  24, 25, 26, 27)  STGF( 7,  28, 29, 30, 31)
        STGF( 8,  32, 33, 34, 35)  STGF( 9,  36, 37, 38, 39)
        STGF(10,  40, 41, 42, 43)  STGF(11,  44, 45, 46, 47)
        STGF(12,  48, 49, 50, 51)  STGF(13,  52, 53, 54, 55)
        STGF(14,  56, 57, 58, 59)  STGF(15,  60, 61, 62, 63)
        STGF(16,  64, 65, 66, 67)  STGF(17,  68, 69, 70, 71)
        STGF(18,  72, 73, 74, 75)  STGF(19,  76, 77, 78, 79)
        STGF(20,  80, 81, 82, 83)  STGF(21,  84, 85, 86, 87)
        STGF(22,  88, 89, 90, 91)  STGF(23,  92, 93, 94, 95)
        STGF(24,  96, 97, 98, 99)  STGF(25, 100,101,102,103)
        STGF(26, 104,105,106,107)  STGF(27, 108,109,110,111)
        STGF(28, 112,113,114,115)  STGF(29, 116,117,118,119)
        STGF(30, 120,121,122,123)  STGF(31, 124,125,126,127)
    }

    __shared__ alignas(16) unsigned short ph[2][L_];  // p (bf16), dbuf
    __shared__ float red[8];
    __shared__ float nmr[4];                          // D ring, lag-2

    // ---- init: s0, exact max N0, p0 ----
    float s = yp[st];
    {
        float v = s;
#pragma unroll
        for (int off = 1; off < 64; off <<= 1) v = fmaxf(v, __shfl_xor(v, off, 64));
        if (i == 0) red[w] = v;
        __syncthreads();
        if (tid == 0) {
            float M = fmaxf(fmaxf(red[0], red[1]), fmaxf(red[2], red[3]));
            nmr[0] = M; nmr[1] = M; nmr[2] = M; nmr[3] = M;
        }
        __syncthreads();
    }
    float NPprev = nmr[0];                 // D_0 = N0
    ph[1][st] = f2bf(__expf(s - NPprev));  // p_0

    // emit regs: e0=E(1), e1=E(2), e2=E(3), e3=E(4)
    float e0 = yp[(size_t)1 * L_ + st];
    float e1 = yp[(size_t)2 * L_ + st];
    float e2 = yp[(size_t)3 * L_ + st];
    float e3 = yp[(size_t)4 * L_ + st];
    __syncthreads();   // p0 + nmr visible

    // main loop: t = 1..508 in 4x bodies (t ≡ 1 mod 4)
    for (int t = 1; t < 509; t += 4) {
        STEP(t + 0, 1, 0, 3, 1, e0)
        STEP(t + 1, 0, 1, 0, 2, e1)
        STEP(t + 2, 1, 0, 1, 3, e2)
        STEP(t + 3, 0, 1, 2, 0, e3)
    }
    // peeled: t = 509, 510, 511
    STEP(509, 1, 0, 3, 1, e0)
    STEP(510, 0, 1, 0, 2, e1)
    STEP(511, 1, 0, 1, 3, e2)

    // ---- final logsumexp over states (all lanes hold unique st) ----
    {
        float v = s;
#pragma unroll
        for (int off = 1; off < 64; off <<= 1) v = fmaxf(v, __shfl_xor(v, off, 64));
        if (i == 0) red[w] = v;
    }
    __syncthreads();
    float M = fmaxf(fmaxf(red[0], red[1]), fmaxf(red[2], red[3]));
    float e = __expf(s - M);
#pragma unroll
    for (int off = 1; off < 64; off <<= 1) e += __shfl_xor(e, off, 64);
    if (i == 0) red[4 + w] = e;
    __syncthreads();
    if (tid == 0)
        out[b] = M + __logf((red[4] + red[5]) + (red[6] + red[7])) - path[b];
}

// ---------------------------------------------------------------------------
extern "C" void kernel_launch(void* const* d_in, const int* in_sizes, int n_in,
                              void* d_out, int out_size, void* d_ws, size_t ws_size,
                              hipStream_t stream) {
    const float* y_true = (const float*)d_in[0];
    const float* y_pre  = (const float*)d_in[1];
    const float* trans  = (const float*)d_in[2];
    float* out = (float*)d_out;

    char* ws = (char*)d_ws;
    unsigned short* ETB = (unsigned short*)ws;            // 128 KiB (frag order)
    int* labels = (int*)(ws + 131072);                    // 256 KiB
    float* path = (float*)(ws + 131072 + 262144);         // 512 B

    hipLaunchKernelGGL(k_exptrans, dim3(L_), dim3(L_), 0, stream, trans, ETB);
    hipLaunchKernelGGL(k_labels, dim3(B_ * T_ / 4), dim3(256), 0, stream, y_true, labels);
    hipLaunchKernelGGL(k_path, dim3(B_), dim3(256), 0, stream, y_pre, trans, labels, path);
    hipLaunchKernelGGL(k_forward, dim3(B_), dim3(256), 0, stream, y_pre, ETB, path, out);
}

// Round 15
// 243.912 us; speedup vs baseline: 1.8946x; 1.0059x over previous
//
#include <hip/hip_runtime.h>
#include <hip/hip_bf16.h>

#define B_ 128
#define T_ 512
#define L_ 256

typedef float f32x4 __attribute__((ext_vector_type(4)));
typedef unsigned uint32x4 __attribute__((ext_vector_type(4)));

__device__ __forceinline__ unsigned short f2bf(float x) {  // RNE f32->bf16
    unsigned u = __builtin_bit_cast(unsigned, x);
    return (unsigned short)((u + 0x7fff + ((u >> 16) & 1)) >> 16);
}

// Physical-AGPR staging (round-9/10-proven; regalloc cannot touch).
#define AW(n, v) asm volatile("v_accvgpr_write_b32 a" #n ", %0" :: "v"(v) : "a" #n)
#define STGF(F, A0, A1, A2, A3) { uint32x4 qq = etb4[vbase + F * 64]; \
    AW(A0, qq[0]); AW(A1, qq[1]); AW(A2, qq[2]); AW(A3, qq[3]); }

// MFMA with B operand in hard-coded physical AGPRs (gfx950 unified RF).
#define MFMA_AB(ACC, AF, LO, HI) \
    asm volatile("v_mfma_f32_16x16x32_bf16 %0, %1, a[" #LO ":" #HI "], %0" \
                 : "+v"(ACC) : "v"(AF))

// Loop barrier WITHOUT vmcnt drain (T4): __syncthreads makes the compiler
// emit s_waitcnt vmcnt(0) before s_barrier, which force-drains our 4-step
// emit prefetch every step (~400cy exposed HBM latency — the round-14 gap).
// LDS ordering only needs lgkmcnt(0). Emit loads stay in flight; their
// s_waitcnt is inserted at USE, 4 steps (~2800cy) after issue.
#define BARRIER() asm volatile("s_waitcnt lgkmcnt(0)\n\ts_barrier" ::: "memory")

// ---------------------------------------------------------------------------
// Kernel A: ETB = bf16(exp(trans)) pre-packed in MFMA B-fragment order.
// (unchanged — HW-verified by round-10 absmax 0.0)
// ---------------------------------------------------------------------------
__global__ __launch_bounds__(256) void k_exptrans(const float* __restrict__ trans,
                                                  unsigned short* __restrict__ ETB) {
    int l = blockIdx.x;          // 256 blocks = rows of trans
    int m = threadIdx.x;         // 256 threads = cols
    unsigned short v = f2bf(__expf(trans[l * L_ + m]));
    unsigned byte = (unsigned)((m >> 4) * 8 + (l >> 5)) * 1024u
                  + (unsigned)(((l >> 3) & 3) * 16 + (m & 15)) * 16u
                  + (unsigned)(((l >> 1) & 3)) * 4u + (unsigned)(l & 1) * 2u;
    *(unsigned short*)((char*)ETB + byte) = v;
}

// ---------------------------------------------------------------------------
// Kernel B: labels from one-hot y_true (one wave per row)
// ---------------------------------------------------------------------------
__global__ __launch_bounds__(256) void k_labels(const float* __restrict__ y_true,
                                                int* __restrict__ labels) {
    int wid = threadIdx.x >> 6, lane = threadIdx.x & 63;
    int r = blockIdx.x * 4 + wid;
    const float4* row = (const float4*)(y_true + (size_t)r * L_);
    float4 v = row[lane];
    int loc = -1;
    if (v.x > 0.5f) loc = lane * 4 + 0;
    if (v.y > 0.5f) loc = lane * 4 + 1;
    if (v.z > 0.5f) loc = lane * 4 + 2;
    if (v.w > 0.5f) loc = lane * 4 + 3;
    unsigned long long m = __ballot(loc >= 0);
    int src = __ffsll(m) - 1;
    int lab = __shfl(loc, src, 64);
    if (lane == 0) labels[r] = lab;
}

// ---------------------------------------------------------------------------
// Kernel C: path_score
// ---------------------------------------------------------------------------
__global__ __launch_bounds__(256) void k_path(const float* __restrict__ y_pre,
                                              const float* __restrict__ trans,
                                              const int* __restrict__ labels,
                                              float* __restrict__ path) {
    int b = blockIdx.x, tid = threadIdx.x;
    const int* lb = labels + b * T_;
    float acc = 0.f;
    for (int t = tid; t < T_; t += 256) {
        int l1 = lb[t];
        acc += y_pre[((size_t)b * T_ + t) * L_ + l1];
        if (t + 1 < T_) acc += trans[l1 * L_ + lb[t + 1]];
    }
#pragma unroll
    for (int off = 1; off < 64; off <<= 1) acc += __shfl_xor(acc, off, 64);
    __shared__ float red[4];
    int wid = tid >> 6, lane = tid & 63;
    if (lane == 0) red[wid] = acc;
    __syncthreads();
    if (tid == 0) path[b] = red[0] + red[1] + red[2] + red[3];
}

// ---------------------------------------------------------------------------
// Kernel D: forward recursion via MFMA — round-14 structure verbatim, with
// the loop barrier swapped to lgkmcnt-only s_barrier (no vmcnt drain).
// ---------------------------------------------------------------------------
#define MFMA32()                                                         \
        MFMA_AB(c0, af0,   0,   3); MFMA_AB(c1, af0,  32,  35);          \
        MFMA_AB(c2, af0,  64,  67); MFMA_AB(c3, af0,  96,  99);          \
        MFMA_AB(c0, af1,   4,   7); MFMA_AB(c1, af1,  36,  39);          \
        MFMA_AB(c2, af1,  68,  71); MFMA_AB(c3, af1, 100, 103);          \
        MFMA_AB(c0, af2,   8,  11); MFMA_AB(c1, af2,  40,  43);          \
        MFMA_AB(c2, af2,  72,  75); MFMA_AB(c3, af2, 104, 107);          \
        MFMA_AB(c0, af3,  12,  15); MFMA_AB(c1, af3,  44,  47);          \
        MFMA_AB(c2, af3,  76,  79); MFMA_AB(c3, af3, 108, 111);          \
        MFMA_AB(c0, af4,  16,  19); MFMA_AB(c1, af4,  48,  51);          \
        MFMA_AB(c2, af4,  80,  83); MFMA_AB(c3, af4, 112, 115);          \
        MFMA_AB(c0, af5,  20,  23); MFMA_AB(c1, af5,  52,  55);          \
        MFMA_AB(c2, af5,  84,  87); MFMA_AB(c3, af5, 116, 119);          \
        MFMA_AB(c0, af6,  24,  27); MFMA_AB(c1, af6,  56,  59);          \
        MFMA_AB(c2, af6,  88,  91); MFMA_AB(c3, af6, 120, 123);          \
        MFMA_AB(c0, af7,  28,  31); MFMA_AB(c1, af7,  60,  63);          \
        MFMA_AB(c2, af7,  92,  95); MFMA_AB(c3, af7, 124, 127);

#define STEP(TT, PH_RD, PH_WR, DSLOT, WSLOT, EREG)                       \
    {                                                                    \
        float Dt = nmr[DSLOT];              /* s_{t-2}[0], 2 barriers old */ \
        float scale = __expf(NPprev + EREG - Dt);  /* runs during MFMA */ \
        const uint32x4* pA = (const uint32x4*)ph[PH_RD];                 \
        uint32x4 af0 = pA[g];      uint32x4 af1 = pA[g + 4];             \
        uint32x4 af2 = pA[g + 8];  uint32x4 af3 = pA[g + 12];            \
        uint32x4 af4 = pA[g + 16]; uint32x4 af5 = pA[g + 20];            \
        uint32x4 af6 = pA[g + 24]; uint32x4 af7 = pA[g + 28];            \
        f32x4 c0 = {0.f,0.f,0.f,0.f}, c1 = {0.f,0.f,0.f,0.f};            \
        f32x4 c2 = {0.f,0.f,0.f,0.f}, c3 = {0.f,0.f,0.f,0.f};            \
        MFMA32()                                                         \
        float val = (g < 2) ? ((g == 0) ? c0[0] : c1[0])                 \
                            : ((g == 2) ? c2[0] : c3[0]);                \
        ph[PH_WR][st] = f2bf(val * scale);   /* p-path: mul+cvt+write */ \
        s = NPprev + __logf(val) + EREG;     /* off p-path */            \
        if (tid == 0) nmr[WSLOT] = s;        /* consumed at t+2 */       \
        NPprev = Dt;                                                     \
        { int tp = (TT) + 4; if (tp > T_ - 1) tp = T_ - 1;               \
          EREG = yp[(size_t)tp * L_ + st]; } /* reload, distance 4 */    \
        BARRIER();                                                       \
    }

__global__ void __launch_bounds__(256, 1)
k_forward(const float* __restrict__ yp_all,
          const unsigned short* __restrict__ ETB,
          const float* __restrict__ path,
          float* __restrict__ out) {
    int b = blockIdx.x, tid = threadIdx.x;
    int w = tid >> 6;            // wave: owns states [64w, 64w+64)
    int i = tid & 63;            // lane
    int g = i >> 4;              // lane group 0..3
    const int st = (w << 6) + i; // this lane's state
    const float* yp = yp_all + (size_t)b * T_ * L_;

    // ---- stage B-fragments (32 x 16B) into physical a0..a127 ----
    {
        const uint32x4* etb4 = (const uint32x4*)ETB;
        int vbase = w * 2048 + i;
        STGF( 0,   0,  1,  2,  3)  STGF( 1,   4,  5,  6,  7)
        STGF( 2,   8,  9, 10, 11)  STGF( 3,  12, 13, 14, 15)
        STGF( 4,  16, 17, 18, 19)  STGF( 5,  20, 21, 22, 23)
        STGF( 6,  24, 25, 26, 27)  STGF( 7,  28, 29, 30, 31)
        STGF( 8,  32, 33, 34, 35)  STGF( 9,  36, 37, 38, 39)
        STGF(10,  40, 41, 42, 43)  STGF(11,  44, 45, 46, 47)
        STGF(12,  48, 49, 50, 51)  STGF(13,  52, 53, 54, 55)
        STGF(14,  56, 57, 58, 59)  STGF(15,  60, 61, 62, 63)
        STGF(16,  64, 65, 66, 67)  STGF(17,  68, 69, 70, 71)
        STGF(18,  72, 73, 74, 75)  STGF(19,  76, 77, 78, 79)
        STGF(20,  80, 81, 82, 83)  STGF(21,  84, 85, 86, 87)
        STGF(22,  88, 89, 90, 91)  STGF(23,  92, 93, 94, 95)
        STGF(24,  96, 97, 98, 99)  STGF(25, 100,101,102,103)
        STGF(26, 104,105,106,107)  STGF(27, 108,109,110,111)
        STGF(28, 112,113,114,115)  STGF(29, 116,117,118,119)
        STGF(30, 120,121,122,123)  STGF(31, 124,125,126,127)
    }

    __shared__ alignas(16) unsigned short ph[2][L_];  // p (bf16), dbuf
    __shared__ float red[8];
    __shared__ float nmr[4];                          // D ring, lag-2

    // ---- init: s0, exact max N0, p0 ----
    float s = yp[st];
    {
        float v = s;
#pragma unroll
        for (int off = 1; off < 64; off <<= 1) v = fmaxf(v, __shfl_xor(v, off, 64));
        if (i == 0) red[w] = v;
        __syncthreads();
        if (tid == 0) {
            float M = fmaxf(fmaxf(red[0], red[1]), fmaxf(red[2], red[3]));
            nmr[0] = M; nmr[1] = M; nmr[2] = M; nmr[3] = M;
        }
        __syncthreads();
    }
    float NPprev = nmr[0];                 // D_0 = N0
    ph[1][st] = f2bf(__expf(s - NPprev));  // p_0

    // emit regs: e0=E(1), e1=E(2), e2=E(3), e3=E(4)
    float e0 = yp[(size_t)1 * L_ + st];
    float e1 = yp[(size_t)2 * L_ + st];
    float e2 = yp[(size_t)3 * L_ + st];
    float e3 = yp[(size_t)4 * L_ + st];
    __syncthreads();   // p0 + nmr visible (one-time vmcnt drain is fine)

    // main loop: t = 1..508 in 4x bodies (t ≡ 1 mod 4)
    for (int t = 1; t < 509; t += 4) {
        STEP(t + 0, 1, 0, 3, 1, e0)
        STEP(t + 1, 0, 1, 0, 2, e1)
        STEP(t + 2, 1, 0, 1, 3, e2)
        STEP(t + 3, 0, 1, 2, 0, e3)
    }
    // peeled: t = 509, 510, 511
    STEP(509, 1, 0, 3, 1, e0)
    STEP(510, 0, 1, 0, 2, e1)
    STEP(511, 1, 0, 1, 3, e2)

    // ---- final logsumexp over states (all lanes hold unique st) ----
    {
        float v = s;
#pragma unroll
        for (int off = 1; off < 64; off <<= 1) v = fmaxf(v, __shfl_xor(v, off, 64));
        if (i == 0) red[w] = v;
    }
    __syncthreads();
    float M = fmaxf(fmaxf(red[0], red[1]), fmaxf(red[2], red[3]));
    float e = __expf(s - M);
#pragma unroll
    for (int off = 1; off < 64; off <<= 1) e += __shfl_xor(e, off, 64);
    if (i == 0) red[4 + w] = e;
    __syncthreads();
    if (tid == 0)
        out[b] = M + __logf((red[4] + red[5]) + (red[6] + red[7])) - path[b];
}

// ---------------------------------------------------------------------------
extern "C" void kernel_launch(void* const* d_in, const int* in_sizes, int n_in,
                              void* d_out, int out_size, void* d_ws, size_t ws_size,
                              hipStream_t stream) {
    const float* y_true = (const float*)d_in[0];
    const float* y_pre  = (const float*)d_in[1];
    const float* trans  = (const float*)d_in[2];
    float* out = (float*)d_out;

    char* ws = (char*)d_ws;
    unsigned short* ETB = (unsigned short*)ws;            // 128 KiB (frag order)
    int* labels = (int*)(ws + 131072);                    // 256 KiB
    float* path = (float*)(ws + 131072 + 262144);         // 512 B

    hipLaunchKernelGGL(k_exptrans, dim3(L_), dim3(L_), 0, stream, trans, ETB);
    hipLaunchKernelGGL(k_labels, dim3(B_ * T_ / 4), dim3(256), 0, stream, y_true, labels);
    hipLaunchKernelGGL(k_path, dim3(B_), dim3(256), 0, stream, y_pre, trans, labels, path);
    hipLaunchKernelGGL(k_forward, dim3(B_), dim3(256), 0, stream, y_pre, ETB, path, out);
}